// Round 1
// baseline (111226.611 us; speedup 1.0000x reference)
//
#include <hip/hip_runtime.h>
#include <math.h>

#define TSTEPS 512
#define DIN 32
#define HID 64
#define NG 256          // 4*H gates
#define RPB 8           // rows per block

__device__ __forceinline__ float sigm(float x) { return 1.0f / (1.0f + __expf(-x)); }
__device__ __forceinline__ float tanh_f(float x) {
    float e = __expf(-2.0f * fabsf(x));
    float t = (1.0f - e) / (1.0f + e);
    return copysignf(t, x);
}

// Block: 512 threads = 8 waves. Waves 0-3: layer-0 gate threads (tid 0..255,
// gate j = tid). Waves 4-7: layer-1 gate threads (gate j = tid-255..).
// Software pipeline: iteration `it` -> layer0 computes step it, layer1 step it-1.
__global__ __launch_bounds__(512, 2)
void lstm_fused_68547678044465(const float* __restrict__ x,
                               const float* __restrict__ Wih0, const float* __restrict__ Whh0,
                               const float* __restrict__ bih0, const float* __restrict__ bhh0,
                               const float* __restrict__ Wih1, const float* __restrict__ Whh1,
                               const float* __restrict__ bih1, const float* __restrict__ bhh1,
                               const float* __restrict__ ln_g, const float* __restrict__ ln_b,
                               const float* __restrict__ fcw, const float* __restrict__ fcb,
                               float* __restrict__ out)
{
    __shared__ __align__(16) float x_lds[8 * RPB * DIN];   // [s][r][k]  8 KB
    __shared__ __align__(16) float h0_lds[2][RPB * HID];   // double-buffered
    __shared__ __align__(16) float h1_lds[RPB * HID];
    __shared__ __align__(16) float gates0[RPB * NG];
    __shared__ __align__(16) float gates1[RPB * NG];

    const int tid = threadIdx.x;
    const int layer = tid >> 8;      // 0 or 1 (wave-uniform)
    const int j = tid & 255;         // gate index within layer
    const int row_base = blockIdx.x * RPB;

    // ---- weights into registers ----
    float4 wi[16], wh[16];
    float bias;
    if (layer == 0) {
        const float4* p = (const float4*)(Wih0 + j * DIN);   // 32 floats
#pragma unroll
        for (int k = 0; k < 8; ++k) wi[k] = p[k];
#pragma unroll
        for (int k = 8; k < 16; ++k) wi[k] = make_float4(0.f, 0.f, 0.f, 0.f);
        const float4* q = (const float4*)(Whh0 + j * HID);   // 64 floats
#pragma unroll
        for (int k = 0; k < 16; ++k) wh[k] = q[k];
        bias = bih0[j] + bhh0[j];
    } else {
        const float4* p = (const float4*)(Wih1 + j * HID);   // 64 floats
#pragma unroll
        for (int k = 0; k < 16; ++k) wi[k] = p[k];
        const float4* q = (const float4*)(Whh1 + j * HID);
#pragma unroll
        for (int k = 0; k < 16; ++k) wh[k] = q[k];
        bias = bih1[j] + bhh1[j];
    }

    // ---- zero states ----
    h0_lds[0][tid] = 0.0f;           // 512 entries, tid covers exactly
    h1_lds[tid] = 0.0f;
    float c_a = 0.0f, c_b = 0.0f;    // cell state lives in update-thread regs

    // ---- x staging: one float4 per thread covers an 8-step group ----
    const int xr = tid >> 6;                 // row 0..7
    const int xq = tid & 63;                 // float4 index in 8*32-float group
    const float* xrow = x + (size_t)(row_base + xr) * (TSTEPS * DIN);
    float4 xreg = ((const float4*)xrow)[xq]; // group 0 (t=0..7)
    {
        const int s = xq >> 3, k4 = xq & 7;
        ((float4*)x_lds)[s * 64 + xr * 8 + k4] = xreg;
    }
    __syncthreads();

    const int e = j & 63;    // element for c/h update
    const int r0 = j >> 6;   // update rows r0 and r0+4

#pragma unroll 1
    for (int it = 0; it <= TSTEPS; ++it) {
        const bool l0a = (layer == 0) && (it < TSTEPS);
        const bool l1a = (layer == 1) && (it >= 1);
        const bool do_load = ((it & 7) == 7) && (it + 1 < TSTEPS);

        // prefetch next 8-step x group into registers (consumed after barrier1)
        if (do_load) xreg = ((const float4*)(xrow + (it + 1) * DIN))[xq];

        // ---------------- phase A: gate dot products ----------------
        float acc[RPB];
        if (l0a) {
#pragma unroll
            for (int r = 0; r < RPB; ++r) acc[r] = bias;
            const float4* xs = (const float4*)x_lds + (it & 7) * 64;  // [r][8]
#pragma unroll
            for (int k = 0; k < 8; ++k) {
                const float4 w = wi[k];
#pragma unroll
                for (int r = 0; r < RPB; ++r) {
                    const float4 v = xs[r * 8 + k];
                    acc[r] = fmaf(w.x, v.x, acc[r]);
                    acc[r] = fmaf(w.y, v.y, acc[r]);
                    acc[r] = fmaf(w.z, v.z, acc[r]);
                    acc[r] = fmaf(w.w, v.w, acc[r]);
                }
            }
            const float4* hs = (const float4*)(h0_lds[it & 1]);       // [r][16]
#pragma unroll
            for (int k = 0; k < 16; ++k) {
                const float4 w = wh[k];
#pragma unroll
                for (int r = 0; r < RPB; ++r) {
                    const float4 v = hs[r * 16 + k];
                    acc[r] = fmaf(w.x, v.x, acc[r]);
                    acc[r] = fmaf(w.y, v.y, acc[r]);
                    acc[r] = fmaf(w.z, v.z, acc[r]);
                    acc[r] = fmaf(w.w, v.w, acc[r]);
                }
            }
            const bool is_tanh = (j >= 128) && (j < 192);   // gate order i,f,g,o
#pragma unroll
            for (int r = 0; r < RPB; ++r) {
                const float gv = is_tanh ? tanh_f(acc[r]) : sigm(acc[r]);
                gates0[r * NG + j] = gv;
            }
        } else if (l1a) {
#pragma unroll
            for (int r = 0; r < RPB; ++r) acc[r] = bias;
            const float4* hs0 = (const float4*)(h0_lds[it & 1]);      // layer-0 output of step it-1
#pragma unroll
            for (int k = 0; k < 16; ++k) {
                const float4 w = wi[k];
#pragma unroll
                for (int r = 0; r < RPB; ++r) {
                    const float4 v = hs0[r * 16 + k];
                    acc[r] = fmaf(w.x, v.x, acc[r]);
                    acc[r] = fmaf(w.y, v.y, acc[r]);
                    acc[r] = fmaf(w.z, v.z, acc[r]);
                    acc[r] = fmaf(w.w, v.w, acc[r]);
                }
            }
            const float4* hs1 = (const float4*)h1_lds;
#pragma unroll
            for (int k = 0; k < 16; ++k) {
                const float4 w = wh[k];
#pragma unroll
                for (int r = 0; r < RPB; ++r) {
                    const float4 v = hs1[r * 16 + k];
                    acc[r] = fmaf(w.x, v.x, acc[r]);
                    acc[r] = fmaf(w.y, v.y, acc[r]);
                    acc[r] = fmaf(w.z, v.z, acc[r]);
                    acc[r] = fmaf(w.w, v.w, acc[r]);
                }
            }
            const bool is_tanh = (j >= 128) && (j < 192);
#pragma unroll
            for (int r = 0; r < RPB; ++r) {
                const float gv = is_tanh ? tanh_f(acc[r]) : sigm(acc[r]);
                gates1[r * NG + j] = gv;
            }
        }
        __syncthreads();   // barrier1: gates visible

        // ---------------- phase B: c/h update ----------------
        if (l0a) {
            float* hd = h0_lds[(it & 1) ^ 1];
            {
                const int r = r0;
                const float iv = gates0[r * NG + e];
                const float fv = gates0[r * NG + 64 + e];
                const float gv = gates0[r * NG + 128 + e];
                const float ov = gates0[r * NG + 192 + e];
                c_a = fmaf(fv, c_a, iv * gv);
                hd[r * HID + e] = ov * tanh_f(c_a);
            }
            {
                const int r = r0 + 4;
                const float iv = gates0[r * NG + e];
                const float fv = gates0[r * NG + 64 + e];
                const float gv = gates0[r * NG + 128 + e];
                const float ov = gates0[r * NG + 192 + e];
                c_b = fmaf(fv, c_b, iv * gv);
                hd[r * HID + e] = ov * tanh_f(c_b);
            }
        } else if (l1a) {
            {
                const int r = r0;
                const float iv = gates1[r * NG + e];
                const float fv = gates1[r * NG + 64 + e];
                const float gv = gates1[r * NG + 128 + e];
                const float ov = gates1[r * NG + 192 + e];
                c_a = fmaf(fv, c_a, iv * gv);
                h1_lds[r * HID + e] = ov * tanh_f(c_a);
            }
            {
                const int r = r0 + 4;
                const float iv = gates1[r * NG + e];
                const float fv = gates1[r * NG + 64 + e];
                const float gv = gates1[r * NG + 128 + e];
                const float ov = gates1[r * NG + 192 + e];
                c_b = fmaf(fv, c_b, iv * gv);
                h1_lds[r * HID + e] = ov * tanh_f(c_b);
            }
        }
        // write prefetched x group (safe: this group's last consumer was phase A)
        if (do_load) {
            const int s = xq >> 3, k4 = xq & 7;
            ((float4*)x_lds)[s * 64 + xr * 8 + k4] = xreg;
        }
        __syncthreads();   // barrier2: h / x visible for next iteration
    }

    // ---------------- epilogue: LayerNorm + FC, wave per row ----------------
    const int wv = tid >> 6;
    const int lane = tid & 63;
    const float v = h1_lds[wv * HID + lane];
    float s1 = v, s2 = v * v;
#pragma unroll
    for (int m = 1; m < 64; m <<= 1) {
        s1 += __shfl_xor(s1, m, 64);
        s2 += __shfl_xor(s2, m, 64);
    }
    const float mu = s1 * (1.0f / HID);
    float var = s2 * (1.0f / HID) - mu * mu;
    var = fmaxf(var, 0.0f);
    const float rs = rsqrtf(var + 1e-5f);
    float p = ((v - mu) * rs * ln_g[lane] + ln_b[lane]) * fcw[lane];
#pragma unroll
    for (int m = 1; m < 64; m <<= 1) p += __shfl_xor(p, m, 64);
    if (lane == 0) out[row_base + wv] = p + fcb[0];
}

extern "C" void kernel_launch(void* const* d_in, const int* in_sizes, int n_in,
                              void* d_out, int out_size, void* d_ws, size_t ws_size,
                              hipStream_t stream) {
    const float* x    = (const float*)d_in[0];
    const float* Wih0 = (const float*)d_in[1];
    const float* Whh0 = (const float*)d_in[2];
    const float* bih0 = (const float*)d_in[3];
    const float* bhh0 = (const float*)d_in[4];
    const float* Wih1 = (const float*)d_in[5];
    const float* Whh1 = (const float*)d_in[6];
    const float* bih1 = (const float*)d_in[7];
    const float* bhh1 = (const float*)d_in[8];
    const float* ln_g = (const float*)d_in[9];
    const float* ln_b = (const float*)d_in[10];
    const float* fcw  = (const float*)d_in[11];
    const float* fcb  = (const float*)d_in[12];

    dim3 grid(2048 / RPB);   // 256 blocks -> 1 per CU
    dim3 block(512);
    hipLaunchKernelGGL(lstm_fused_68547678044465, grid, block, 0, stream,
                       x, Wih0, Whh0, bih0, bhh0, Wih1, Whh1, bih1, bhh1,
                       ln_g, ln_b, fcw, fcb, (float*)d_out);
}

// Round 2
// 103402.307 us; speedup vs baseline: 1.0757x; 1.0757x over previous
//
#include <hip/hip_runtime.h>
#include <math.h>

#define TSTEPS 512
#define DIN 32
#define HID 64
#define NG 256          // 4*H gates
#define RPB 8           // rows per block

__device__ __forceinline__ float sigm(float x) { return 1.0f / (1.0f + __expf(-x)); }
__device__ __forceinline__ float tanh_f(float x) {
    float e = __expf(-2.0f * fabsf(x));
    float t = (1.0f - e) / (1.0f + e);
    return copysignf(t, x);
}

// Block: 512 threads = 8 waves. Waves 0-3: layer-0 gate threads (tid 0..255,
// gate j = tid). Waves 4-7: layer-1 gate threads (gate j = tid-256).
// Software pipeline: iteration `it` -> layer0 computes step it, layer1 step it-1.
// NOTE: __launch_bounds__(512) with NO min-occupancy arg: a 512-thread block
// needs 2 waves/SIMD resident, so the compiler caps at 256 VGPR/wave — enough
// for the 128 weight VGPRs without spilling. (512,2) was treated as 2 blocks/CU
// -> 128-VGPR cap -> 270 GB of scratch spill traffic per dispatch.
__global__ __launch_bounds__(512)
void lstm_fused_68547678044465(const float* __restrict__ x,
                               const float* __restrict__ Wih0, const float* __restrict__ Whh0,
                               const float* __restrict__ bih0, const float* __restrict__ bhh0,
                               const float* __restrict__ Wih1, const float* __restrict__ Whh1,
                               const float* __restrict__ bih1, const float* __restrict__ bhh1,
                               const float* __restrict__ ln_g, const float* __restrict__ ln_b,
                               const float* __restrict__ fcw, const float* __restrict__ fcb,
                               float* __restrict__ out)
{
    __shared__ __align__(16) float x_lds[8 * RPB * DIN];   // [s][r][k]  8 KB
    __shared__ __align__(16) float h0_lds[2][RPB * HID];   // double-buffered
    __shared__ __align__(16) float h1_lds[RPB * HID];
    __shared__ __align__(16) float gates0[RPB * NG];
    __shared__ __align__(16) float gates1[RPB * NG];

    const int tid = threadIdx.x;
    const int layer = tid >> 8;      // 0 or 1 (wave-uniform)
    const int j = tid & 255;         // gate index within layer
    const int row_base = blockIdx.x * RPB;

    // ---- weights into registers ----
    float4 wi[16], wh[16];
    float bias;
    if (layer == 0) {
        const float4* p = (const float4*)(Wih0 + j * DIN);   // 32 floats
#pragma unroll
        for (int k = 0; k < 8; ++k) wi[k] = p[k];
        const float4* q = (const float4*)(Whh0 + j * HID);   // 64 floats
#pragma unroll
        for (int k = 0; k < 16; ++k) wh[k] = q[k];
        bias = bih0[j] + bhh0[j];
    } else {
        const float4* p = (const float4*)(Wih1 + j * HID);   // 64 floats
#pragma unroll
        for (int k = 0; k < 16; ++k) wi[k] = p[k];
        const float4* q = (const float4*)(Whh1 + j * HID);
#pragma unroll
        for (int k = 0; k < 16; ++k) wh[k] = q[k];
        bias = bih1[j] + bhh1[j];
    }

    // ---- zero states ----
    h0_lds[0][tid] = 0.0f;           // 512 entries, tid covers exactly
    h1_lds[tid] = 0.0f;
    float c_a = 0.0f, c_b = 0.0f;    // cell state lives in update-thread regs

    // ---- x staging: one float4 per thread covers an 8-step group ----
    const int xr = tid >> 6;                 // row 0..7
    const int xq = tid & 63;                 // float4 index in 8*32-float group
    const float* xrow = x + (size_t)(row_base + xr) * (TSTEPS * DIN);
    float4 xreg = ((const float4*)xrow)[xq]; // group 0 (t=0..7)
    {
        const int s = xq >> 3, k4 = xq & 7;
        ((float4*)x_lds)[s * 64 + xr * 8 + k4] = xreg;
    }
    __syncthreads();

    const int e = j & 63;    // element for c/h update
    const int r0 = j >> 6;   // update rows r0 and r0+4

#pragma unroll 1
    for (int it = 0; it <= TSTEPS; ++it) {
        const bool l0a = (layer == 0) && (it < TSTEPS);
        const bool l1a = (layer == 1) && (it >= 1);
        const bool do_load = ((it & 7) == 7) && (it + 1 < TSTEPS);

        // prefetch next 8-step x group into registers (consumed after barrier1)
        if (do_load) xreg = ((const float4*)(xrow + (it + 1) * DIN))[xq];

        // ---------------- phase A: gate dot products ----------------
        float acc[RPB];
        if (l0a) {
#pragma unroll
            for (int r = 0; r < RPB; ++r) acc[r] = bias;
            const float4* xs = (const float4*)x_lds + (it & 7) * 64;  // [r][8]
#pragma unroll
            for (int k = 0; k < 8; ++k) {
                const float4 w = wi[k];
#pragma unroll
                for (int r = 0; r < RPB; ++r) {
                    const float4 v = xs[r * 8 + k];
                    acc[r] = fmaf(w.x, v.x, acc[r]);
                    acc[r] = fmaf(w.y, v.y, acc[r]);
                    acc[r] = fmaf(w.z, v.z, acc[r]);
                    acc[r] = fmaf(w.w, v.w, acc[r]);
                }
            }
            const float4* hs = (const float4*)(h0_lds[it & 1]);       // [r][16]
#pragma unroll
            for (int k = 0; k < 16; ++k) {
                const float4 w = wh[k];
#pragma unroll
                for (int r = 0; r < RPB; ++r) {
                    const float4 v = hs[r * 16 + k];
                    acc[r] = fmaf(w.x, v.x, acc[r]);
                    acc[r] = fmaf(w.y, v.y, acc[r]);
                    acc[r] = fmaf(w.z, v.z, acc[r]);
                    acc[r] = fmaf(w.w, v.w, acc[r]);
                }
            }
            const bool is_tanh = (j >= 128) && (j < 192);   // gate order i,f,g,o
#pragma unroll
            for (int r = 0; r < RPB; ++r) {
                const float gv = is_tanh ? tanh_f(acc[r]) : sigm(acc[r]);
                gates0[r * NG + j] = gv;
            }
        } else if (l1a) {
#pragma unroll
            for (int r = 0; r < RPB; ++r) acc[r] = bias;
            const float4* hs0 = (const float4*)(h0_lds[it & 1]);      // layer-0 output of step it-1
#pragma unroll
            for (int k = 0; k < 16; ++k) {
                const float4 w = wi[k];
#pragma unroll
                for (int r = 0; r < RPB; ++r) {
                    const float4 v = hs0[r * 16 + k];
                    acc[r] = fmaf(w.x, v.x, acc[r]);
                    acc[r] = fmaf(w.y, v.y, acc[r]);
                    acc[r] = fmaf(w.z, v.z, acc[r]);
                    acc[r] = fmaf(w.w, v.w, acc[r]);
                }
            }
            const float4* hs1 = (const float4*)h1_lds;
#pragma unroll
            for (int k = 0; k < 16; ++k) {
                const float4 w = wh[k];
#pragma unroll
                for (int r = 0; r < RPB; ++r) {
                    const float4 v = hs1[r * 16 + k];
                    acc[r] = fmaf(w.x, v.x, acc[r]);
                    acc[r] = fmaf(w.y, v.y, acc[r]);
                    acc[r] = fmaf(w.z, v.z, acc[r]);
                    acc[r] = fmaf(w.w, v.w, acc[r]);
                }
            }
            const bool is_tanh = (j >= 128) && (j < 192);
#pragma unroll
            for (int r = 0; r < RPB; ++r) {
                const float gv = is_tanh ? tanh_f(acc[r]) : sigm(acc[r]);
                gates1[r * NG + j] = gv;
            }
        }
        __syncthreads();   // barrier1: gates visible

        // ---------------- phase B: c/h update ----------------
        if (l0a) {
            float* hd = h0_lds[(it & 1) ^ 1];
            {
                const int r = r0;
                const float iv = gates0[r * NG + e];
                const float fv = gates0[r * NG + 64 + e];
                const float gv = gates0[r * NG + 128 + e];
                const float ov = gates0[r * NG + 192 + e];
                c_a = fmaf(fv, c_a, iv * gv);
                hd[r * HID + e] = ov * tanh_f(c_a);
            }
            {
                const int r = r0 + 4;
                const float iv = gates0[r * NG + e];
                const float fv = gates0[r * NG + 64 + e];
                const float gv = gates0[r * NG + 128 + e];
                const float ov = gates0[r * NG + 192 + e];
                c_b = fmaf(fv, c_b, iv * gv);
                hd[r * HID + e] = ov * tanh_f(c_b);
            }
        } else if (l1a) {
            {
                const int r = r0;
                const float iv = gates1[r * NG + e];
                const float fv = gates1[r * NG + 64 + e];
                const float gv = gates1[r * NG + 128 + e];
                const float ov = gates1[r * NG + 192 + e];
                c_a = fmaf(fv, c_a, iv * gv);
                h1_lds[r * HID + e] = ov * tanh_f(c_a);
            }
            {
                const int r = r0 + 4;
                const float iv = gates1[r * NG + e];
                const float fv = gates1[r * NG + 64 + e];
                const float gv = gates1[r * NG + 128 + e];
                const float ov = gates1[r * NG + 192 + e];
                c_b = fmaf(fv, c_b, iv * gv);
                h1_lds[r * HID + e] = ov * tanh_f(c_b);
            }
        }
        // write prefetched x group (safe: this group's last consumer was phase A)
        if (do_load) {
            const int s = xq >> 3, k4 = xq & 7;
            ((float4*)x_lds)[s * 64 + xr * 8 + k4] = xreg;
        }
        __syncthreads();   // barrier2: h / x visible for next iteration
    }

    // ---------------- epilogue: LayerNorm + FC, wave per row ----------------
    const int wv = tid >> 6;
    const int lane = tid & 63;
    const float v = h1_lds[wv * HID + lane];
    float s1 = v, s2 = v * v;
#pragma unroll
    for (int m = 1; m < 64; m <<= 1) {
        s1 += __shfl_xor(s1, m, 64);
        s2 += __shfl_xor(s2, m, 64);
    }
    const float mu = s1 * (1.0f / HID);
    float var = s2 * (1.0f / HID) - mu * mu;
    var = fmaxf(var, 0.0f);
    const float rs = rsqrtf(var + 1e-5f);
    float p = ((v - mu) * rs * ln_g[lane] + ln_b[lane]) * fcw[lane];
#pragma unroll
    for (int m = 1; m < 64; m <<= 1) p += __shfl_xor(p, m, 64);
    if (lane == 0) out[row_base + wv] = p + fcb[0];
}

extern "C" void kernel_launch(void* const* d_in, const int* in_sizes, int n_in,
                              void* d_out, int out_size, void* d_ws, size_t ws_size,
                              hipStream_t stream) {
    const float* x    = (const float*)d_in[0];
    const float* Wih0 = (const float*)d_in[1];
    const float* Whh0 = (const float*)d_in[2];
    const float* bih0 = (const float*)d_in[3];
    const float* bhh0 = (const float*)d_in[4];
    const float* Wih1 = (const float*)d_in[5];
    const float* Whh1 = (const float*)d_in[6];
    const float* bih1 = (const float*)d_in[7];
    const float* bhh1 = (const float*)d_in[8];
    const float* ln_g = (const float*)d_in[9];
    const float* ln_b = (const float*)d_in[10];
    const float* fcw  = (const float*)d_in[11];
    const float* fcb  = (const float*)d_in[12];

    dim3 grid(2048 / RPB);   // 256 blocks -> 1 per CU
    dim3 block(512);
    hipLaunchKernelGGL(lstm_fused_68547678044465, grid, block, 0, stream,
                       x, Wih0, Whh0, bih0, bhh0, Wih1, Whh1, bih1, bhh1,
                       ln_g, ln_b, fcw, fcb, (float*)d_out);
}

// Round 4
// 3732.669 us; speedup vs baseline: 29.7981x; 27.7020x over previous
//
#include <hip/hip_runtime.h>
#include <math.h>

#define TSTEPS 512
#define DIN 32
#define HID 64
#define NG 256          // 4*H gates
#define RPB 8           // rows per block

__device__ __forceinline__ float sigm(float x) { return 1.0f / (1.0f + __expf(-x)); }
__device__ __forceinline__ float tanh_f(float x) {
    float e = __expf(-2.0f * fabsf(x));
    float t = (1.0f - e) / (1.0f + e);
    return copysignf(t, x);
}

// hygienic fma4 (the old FMA4 macro's param `w` token-collided with `.w` member access)
__device__ __forceinline__ void fma4(float& a, const float4& wv, const float4& vv) {
    a = fmaf(wv.x, vv.x, a);
    a = fmaf(wv.y, vv.y, a);
    a = fmaf(wv.z, vv.z, a);
    a = fmaf(wv.w, vv.w, a);
}

// 256 blocks x 1024 threads. Waves 0-7: layer0, waves 8-15: layer1 (pipelined:
// iteration it -> layer0 computes step it, layer1 step it-1).
// K-split: within a wave, lanes l and l^32 hold the two halves of one gate's
// weight row (<=16 named float4 each -> 64 VGPRs, no arrays -> nothing to spill).
// Partial dots combine via __shfl_xor(.,32).
__global__ __launch_bounds__(1024)
void lstm_fused_68547678044465(const float* __restrict__ x,
                               const float* __restrict__ Wih0, const float* __restrict__ Whh0,
                               const float* __restrict__ bih0, const float* __restrict__ bhh0,
                               const float* __restrict__ Wih1, const float* __restrict__ Whh1,
                               const float* __restrict__ bih1, const float* __restrict__ bhh1,
                               const float* __restrict__ ln_g, const float* __restrict__ ln_b,
                               const float* __restrict__ fcw, const float* __restrict__ fcb,
                               float* __restrict__ out)
{
    __shared__ __align__(16) float x_lds[8 * RPB * DIN];   // [s][r][k]  8 KB
    __shared__ __align__(16) float h0_lds[2][RPB * HID];   // 4 KB, double-buffered
    __shared__ __align__(16) float h1_lds[RPB * HID];      // 2 KB
    __shared__ __align__(16) float gates0[RPB * NG];       // 8 KB
    __shared__ __align__(16) float gates1[RPB * NG];       // 8 KB

    const int tid   = threadIdx.x;
    const int layer = tid >> 9;          // 0/1, wave-uniform
    const int u     = tid & 511;         // index within layer
    const int wl    = u >> 6;            // layer-local wave 0..7 (uniform)
    const int lane  = tid & 63;
    const int seg   = lane >> 5;         // K-half 0/1 (lanes 0-31 vs 32-63)
    const int gate  = wl * 32 + (lane & 31);   // gate 0..255
    const bool is_tanh = (wl == 4) || (wl == 5);  // gates 128..191 = g-gate
    const int row_base = blockIdx.x * RPB;

    // ---- weights into NAMED registers (no arrays) ----
    float4 w0, w1, w2, w3, w4, w5, w6, w7, w8, w9, w10, w11, w12, w13, w14, w15;
    float aInit;
    if (layer == 0) {
        const float4* Wx = (const float4*)(Wih0 + gate * DIN);   // 8 float4
        const float4* Wh = (const float4*)(Whh0 + gate * HID);   // 16 float4
        if (seg == 0) {   // x[0:32] + h[0:16]
            w0 = Wx[0]; w1 = Wx[1]; w2 = Wx[2]; w3 = Wx[3];
            w4 = Wx[4]; w5 = Wx[5]; w6 = Wx[6]; w7 = Wx[7];
            w8 = Wh[0]; w9 = Wh[1]; w10 = Wh[2]; w11 = Wh[3];
            aInit = bih0[gate] + bhh0[gate];
        } else {          // h[16:64]
            w0 = Wh[4];  w1 = Wh[5];  w2 = Wh[6];  w3 = Wh[7];
            w4 = Wh[8];  w5 = Wh[9];  w6 = Wh[10]; w7 = Wh[11];
            w8 = Wh[12]; w9 = Wh[13]; w10 = Wh[14]; w11 = Wh[15];
            aInit = 0.0f;
        }
        w12 = w13 = w14 = w15 = make_float4(0.f, 0.f, 0.f, 0.f);
    } else {
        const float4* Wa = (const float4*)((seg ? Whh1 : Wih1) + gate * HID);
        w0 = Wa[0];  w1 = Wa[1];  w2 = Wa[2];  w3 = Wa[3];
        w4 = Wa[4];  w5 = Wa[5];  w6 = Wa[6];  w7 = Wa[7];
        w8 = Wa[8];  w9 = Wa[9];  w10 = Wa[10]; w11 = Wa[11];
        w12 = Wa[12]; w13 = Wa[13]; w14 = Wa[14]; w15 = Wa[15];
        aInit = seg ? 0.0f : (bih1[gate] + bhh1[gate]);
    }

    // ---- zero states ----
    if (tid < 512) { h0_lds[0][tid] = 0.0f; h1_lds[tid] = 0.0f; }
    float c = 0.0f;                       // one cell element per thread

    // phase-B cell mapping: thread u -> (row rr, element e) of its layer
    const int rr = u >> 6;
    const int e  = u & 63;

    // ---- x staging: threads 0..511 load one float4 per 8-step group ----
    const int xr = (tid >> 6) & 7;
    const int xq = tid & 63;
    const float* xrow = x + (size_t)(row_base + xr) * (TSTEPS * DIN);
    float4 xreg;
    if (tid < 512) {
        xreg = ((const float4*)xrow)[xq];   // group 0 (t=0..7)
        const int s = xq >> 3, k4 = xq & 7;
        ((float4*)x_lds)[s * 64 + xr * 8 + k4] = xreg;
    }
    __syncthreads();

    const int segB = seg ? 12 : 0;

#pragma unroll 1
    for (int it = 0; it <= TSTEPS; ++it) {
        const bool l0a = (layer == 0) && (it < TSTEPS);
        const bool l1a = (layer == 1) && (it >= 1);
        const bool do_load = ((it & 7) == 7) && (it + 1 < TSTEPS) && (tid < 512);

        if (do_load) xreg = ((const float4*)(xrow + (it + 1) * DIN))[xq];

        // ---------------- phase A: gate half-dots + combine ----------------
        float acc[RPB];
        if (l0a) {
            const float4* xs4 = (const float4*)x_lds + (it & 7) * 64;  // [r][8]
            const float4* hs4 = (const float4*)(h0_lds[it & 1]);       // [r][16]
#pragma unroll 2
            for (int r = 0; r < RPB; ++r) {
                const float4* pA = seg ? (hs4 + r * 16 + 4) : (xs4 + r * 8);
                const float4* pB = hs4 + r * 16 + segB;
                float a0 = aInit, a1 = 0.0f;
                fma4(a0, w0, pA[0]); fma4(a1, w1, pA[1]);
                fma4(a0, w2, pA[2]); fma4(a1, w3, pA[3]);
                fma4(a0, w4, pA[4]); fma4(a1, w5, pA[5]);
                fma4(a0, w6, pA[6]); fma4(a1, w7, pA[7]);
                fma4(a0, w8, pB[0]); fma4(a1, w9, pB[1]);
                fma4(a0, w10, pB[2]); fma4(a1, w11, pB[3]);
                acc[r] = a0 + a1;
            }
#pragma unroll
            for (int r = 0; r < RPB; ++r) acc[r] += __shfl_xor(acc[r], 32, 64);
            const int rb = seg << 2;
#pragma unroll
            for (int q = 0; q < 4; ++q) {
                const int r = rb + q;
                const float gv = is_tanh ? tanh_f(acc[r]) : sigm(acc[r]);
                gates0[r * NG + gate] = gv;
            }
        } else if (l1a) {
            const float4* h0s4 = (const float4*)(h0_lds[it & 1]);  // layer0 out, step it-1
            const float4* h1s4 = (const float4*)h1_lds;
            const float4* base = seg ? h1s4 : h0s4;
#pragma unroll 2
            for (int r = 0; r < RPB; ++r) {
                const float4* pA = base + r * 16;
                float a0 = aInit, a1 = 0.0f;
                fma4(a0, w0, pA[0]);  fma4(a1, w1, pA[1]);
                fma4(a0, w2, pA[2]);  fma4(a1, w3, pA[3]);
                fma4(a0, w4, pA[4]);  fma4(a1, w5, pA[5]);
                fma4(a0, w6, pA[6]);  fma4(a1, w7, pA[7]);
                fma4(a0, w8, pA[8]);  fma4(a1, w9, pA[9]);
                fma4(a0, w10, pA[10]); fma4(a1, w11, pA[11]);
                fma4(a0, w12, pA[12]); fma4(a1, w13, pA[13]);
                fma4(a0, w14, pA[14]); fma4(a1, w15, pA[15]);
                acc[r] = a0 + a1;
            }
#pragma unroll
            for (int r = 0; r < RPB; ++r) acc[r] += __shfl_xor(acc[r], 32, 64);
            const int rb = seg << 2;
#pragma unroll
            for (int q = 0; q < 4; ++q) {
                const int r = rb + q;
                const float gv = is_tanh ? tanh_f(acc[r]) : sigm(acc[r]);
                gates1[r * NG + gate] = gv;
            }
        }
        __syncthreads();   // barrier1: gates visible

        // ---------------- phase B: c/h update (1 cell per thread) ----------------
        if (l0a) {
            const float iv = gates0[rr * NG + e];
            const float fv = gates0[rr * NG + 64 + e];
            const float gv = gates0[rr * NG + 128 + e];
            const float ov = gates0[rr * NG + 192 + e];
            c = fmaf(fv, c, iv * gv);
            h0_lds[(it & 1) ^ 1][rr * HID + e] = ov * tanh_f(c);
        } else if (l1a) {
            const float iv = gates1[rr * NG + e];
            const float fv = gates1[rr * NG + 64 + e];
            const float gv = gates1[rr * NG + 128 + e];
            const float ov = gates1[rr * NG + 192 + e];
            c = fmaf(fv, c, iv * gv);
            h1_lds[rr * HID + e] = ov * tanh_f(c);
        }
        if (do_load) {   // write prefetched x group (its last reader was phase A)
            const int s = xq >> 3, k4 = xq & 7;
            ((float4*)x_lds)[s * 64 + xr * 8 + k4] = xreg;
        }
        __syncthreads();   // barrier2: h / x visible for next iteration
    }

    // ---------------- epilogue: LayerNorm + FC, wave per row ----------------
    if (tid < 512) {
        const int wv = tid >> 6;
        const float v = h1_lds[wv * HID + lane];
        float s1 = v, s2 = v * v;
#pragma unroll
        for (int m = 1; m < 64; m <<= 1) {
            s1 += __shfl_xor(s1, m, 64);
            s2 += __shfl_xor(s2, m, 64);
        }
        const float mu = s1 * (1.0f / HID);
        float var = s2 * (1.0f / HID) - mu * mu;
        var = fmaxf(var, 0.0f);
        const float rs = rsqrtf(var + 1e-5f);
        float p = ((v - mu) * rs * ln_g[lane] + ln_b[lane]) * fcw[lane];
#pragma unroll
        for (int m = 1; m < 64; m <<= 1) p += __shfl_xor(p, m, 64);
        if (lane == 0) out[row_base + wv] = p + fcb[0];
    }
}

extern "C" void kernel_launch(void* const* d_in, const int* in_sizes, int n_in,
                              void* d_out, int out_size, void* d_ws, size_t ws_size,
                              hipStream_t stream) {
    const float* x    = (const float*)d_in[0];
    const float* Wih0 = (const float*)d_in[1];
    const float* Whh0 = (const float*)d_in[2];
    const float* bih0 = (const float*)d_in[3];
    const float* bhh0 = (const float*)d_in[4];
    const float* Wih1 = (const float*)d_in[5];
    const float* Whh1 = (const float*)d_in[6];
    const float* bih1 = (const float*)d_in[7];
    const float* bhh1 = (const float*)d_in[8];
    const float* ln_g = (const float*)d_in[9];
    const float* ln_b = (const float*)d_in[10];
    const float* fcw  = (const float*)d_in[11];
    const float* fcb  = (const float*)d_in[12];

    dim3 grid(2048 / RPB);   // 256 blocks -> 1 per CU
    dim3 block(1024);
    hipLaunchKernelGGL(lstm_fused_68547678044465, grid, block, 0, stream,
                       x, Wih0, Whh0, bih0, bhh0, Wih1, Whh1, bih1, bhh1,
                       ln_g, ln_b, fcw, fcb, (float*)d_out);
}

// Round 5
// 650.701 us; speedup vs baseline: 170.9334x; 5.7364x over previous
//
#include <hip/hip_runtime.h>
#include <math.h>

#define TSTEPS 512
#define RPB 8
#define L2E 1.4426950408889634f

typedef __attribute__((ext_vector_type(8))) short short8;
typedef __attribute__((ext_vector_type(4))) short short4v;
typedef __attribute__((ext_vector_type(4))) float f32x4;
typedef __bf16 bf16x8 __attribute__((ext_vector_type(8)));

__device__ __forceinline__ short f2bf(float f) {            // RNE float->bf16
    union { float f; unsigned u; } v; v.f = f;
    return (short)((v.u + 0x7FFFu + ((v.u >> 16) & 1u)) >> 16);
}
__device__ __forceinline__ float rcp_f(float x) { return __builtin_amdgcn_rcpf(x); }
__device__ __forceinline__ float ex2(float x)   { return __builtin_amdgcn_exp2f(x); }
__device__ __forceinline__ float sigm_p(float v) {          // v = pre * log2e
    return rcp_f(1.0f + ex2(-v));
}
__device__ __forceinline__ float tanh_p(float v) {          // v = pre * 2*log2e
    float e = ex2(-fabsf(v));
    return copysignf((1.0f - e) * rcp_f(1.0f + e), v);
}
__device__ __forceinline__ f32x4 mfma16(bf16x8 a, bf16x8 b, f32x4 c) {
    return __builtin_amdgcn_mfma_f32_16x16x32_bf16(a, b, c, 0, 0, 0);
}

// 256 blocks x 512 threads (8 waves). Waves 0-3: layer0, waves 4-7: layer1,
// pipelined (iter it: layer0 computes step it, layer1 step it-1).
// Wave wl owns gate tiles {64g + 16*wl}, g=0..3 (i,f,g,o) -> each lane holds
// i,f,g,o for the same cells -> c/h update fully in-register, c stays fp32.
// Weights as B-fragments in registers (named, no arrays). A (x,h) in LDS as
// bf16, rows padded to 40/72 elems (uniform bank spread for A-frag b128 reads).
// log2e folded into weights/biases: sigmoid gates scaled by log2e, g-gate by
// 2*log2e, so activations use v_exp_f32 (exp2) directly.
__global__ __launch_bounds__(512)
void lstm_mfma_68547678044465(const float* __restrict__ x,
                              const float* __restrict__ Wih0, const float* __restrict__ Whh0,
                              const float* __restrict__ bih0, const float* __restrict__ bhh0,
                              const float* __restrict__ Wih1, const float* __restrict__ Whh1,
                              const float* __restrict__ bih1, const float* __restrict__ bhh1,
                              const float* __restrict__ ln_g, const float* __restrict__ ln_b,
                              const float* __restrict__ fcw, const float* __restrict__ fcb,
                              float* __restrict__ out)
{
    __shared__ __align__(16) short Xb[2][8][16][40];   // x bf16, dbuf x 8 steps, rows 8-15 zero
    __shared__ __align__(16) short H0s[2][16][72];     // h0 bf16 by step parity
    __shared__ __align__(16) short H1s[2][16][72];     // h1 bf16 by step parity
    __shared__ __align__(16) float HF[8][64];          // final h1 fp32 for LN

    const int tid  = threadIdx.x;
    const int wave = tid >> 6, lane = tid & 63;
    const int m = lane & 15, q = lane >> 4;            // A/B frag: n|m = lane&15, k = q*8+j
    const int layer = wave >> 2, wl = wave & 3;
    const int rb = blockIdx.x * RPB;

    // ---- B-fragments: 4 tiles (i,f,g,o) x 4 K-chunks, named registers ----
    bf16x8 B00, B01, B02, B03, B10, B11, B12, B13,
           B20, B21, B22, B23, B30, B31, B32, B33;
    float b0, b1, b2, b3;
    {
        auto loadB = [&](const float* wrow, int koff, float sc) -> bf16x8 {
            const float4 lo = *(const float4*)(wrow + koff);
            const float4 hi = *(const float4*)(wrow + koff + 4);
            short8 r;
            r[0] = f2bf(lo.x * sc); r[1] = f2bf(lo.y * sc);
            r[2] = f2bf(lo.z * sc); r[3] = f2bf(lo.w * sc);
            r[4] = f2bf(hi.x * sc); r[5] = f2bf(hi.y * sc);
            r[6] = f2bf(hi.z * sc); r[7] = f2bf(hi.w * sc);
            return (bf16x8)r;
        };
        const int gi = wl * 16 + m;                     // gate within 64-group
        if (layer == 0) {
            // K=96: chunk0 = Wih0 (32 cols), chunks 1,2 = Whh0 (64 cols)
            const float sc0 = L2E, sc2 = 2.0f * L2E;
            const int g0 = gi, g1 = 64 + gi, g2 = 128 + gi, g3 = 192 + gi;
            B00 = loadB(Wih0 + g0 * 32, q * 8, sc0);
            B01 = loadB(Whh0 + g0 * 64, q * 8, sc0);
            B02 = loadB(Whh0 + g0 * 64, 32 + q * 8, sc0);
            B10 = loadB(Wih0 + g1 * 32, q * 8, sc0);
            B11 = loadB(Whh0 + g1 * 64, q * 8, sc0);
            B12 = loadB(Whh0 + g1 * 64, 32 + q * 8, sc0);
            B20 = loadB(Wih0 + g2 * 32, q * 8, sc2);
            B21 = loadB(Whh0 + g2 * 64, q * 8, sc2);
            B22 = loadB(Whh0 + g2 * 64, 32 + q * 8, sc2);
            B30 = loadB(Wih0 + g3 * 32, q * 8, sc0);
            B31 = loadB(Whh0 + g3 * 64, q * 8, sc0);
            B32 = loadB(Whh0 + g3 * 64, 32 + q * 8, sc0);
            short8 z = {0,0,0,0,0,0,0,0};
            B03 = (bf16x8)z; B13 = (bf16x8)z; B23 = (bf16x8)z; B33 = (bf16x8)z;
            b0 = (bih0[g0] + bhh0[g0]) * sc0;
            b1 = (bih0[g1] + bhh0[g1]) * sc0;
            b2 = (bih0[g2] + bhh0[g2]) * sc2;
            b3 = (bih0[g3] + bhh0[g3]) * sc0;
        } else {
            // K=128: chunks 0,1 = Wih1 (h0 input), chunks 2,3 = Whh1 (h1)
            const float sc0 = L2E, sc2 = 2.0f * L2E;
            const int g0 = gi, g1 = 64 + gi, g2 = 128 + gi, g3 = 192 + gi;
            B00 = loadB(Wih1 + g0 * 64, q * 8, sc0);
            B01 = loadB(Wih1 + g0 * 64, 32 + q * 8, sc0);
            B02 = loadB(Whh1 + g0 * 64, q * 8, sc0);
            B03 = loadB(Whh1 + g0 * 64, 32 + q * 8, sc0);
            B10 = loadB(Wih1 + g1 * 64, q * 8, sc0);
            B11 = loadB(Wih1 + g1 * 64, 32 + q * 8, sc0);
            B12 = loadB(Whh1 + g1 * 64, q * 8, sc0);
            B13 = loadB(Whh1 + g1 * 64, 32 + q * 8, sc0);
            B20 = loadB(Wih1 + g2 * 64, q * 8, sc2);
            B21 = loadB(Wih1 + g2 * 64, 32 + q * 8, sc2);
            B22 = loadB(Whh1 + g2 * 64, q * 8, sc2);
            B23 = loadB(Whh1 + g2 * 64, 32 + q * 8, sc2);
            B30 = loadB(Wih1 + g3 * 64, q * 8, sc0);
            B31 = loadB(Wih1 + g3 * 64, 32 + q * 8, sc0);
            B32 = loadB(Whh1 + g3 * 64, q * 8, sc0);
            B33 = loadB(Whh1 + g3 * 64, 32 + q * 8, sc0);
            b0 = (bih1[g0] + bhh1[g0]) * sc0;
            b1 = (bih1[g1] + bhh1[g1]) * sc0;
            b2 = (bih1[g2] + bhh1[g2]) * sc2;
            b3 = (bih1[g3] + bhh1[g3]) * sc0;
        }
    }

    // ---- zero LDS (incl. rows 8-15 read by garbage quads) ----
    { short* p = &Xb[0][0][0][0];  for (int i = tid; i < 2*8*16*40; i += 512) p[i] = 0; }
    { short* p = &H0s[0][0][0];    for (int i = tid; i < 2*16*72;   i += 512) p[i] = 0; }
    { short* p = &H1s[0][0][0];    for (int i = tid; i < 2*16*72;   i += 512) p[i] = 0; }

    // ---- x staging setup: thread -> (step-in-group ss, row sm, float4 kq) ----
    const int ss = tid >> 6, sm = (tid >> 3) & 7, kq = tid & 7;
    const float* xg = x + (size_t)(rb + sm) * (TSTEPS * 32) + ss * 32 + kq * 4;
    {   // stage group 0 (steps 0-7) into Xb[0]
        const float4 v = *(const float4*)(xg);
        short4v pk; pk[0] = f2bf(v.x); pk[1] = f2bf(v.y); pk[2] = f2bf(v.z); pk[3] = f2bf(v.w);
        *(short4v*)(&Xb[0][ss][sm][kq * 4]) = pk;
    }
    __syncthreads();

    float c0 = 0.0f, c1 = 0.0f, c2 = 0.0f, c3 = 0.0f;   // fp32 cell, rows q*4+r
    const int aoffX = m * 40 + q * 8;
    const int aoffH = m * 72 + q * 8;
    const int cidx  = wl * 16 + m;

#pragma unroll 1
    for (int it = 0; it <= TSTEPS; ++it) {
        const bool l0 = (layer == 0) && (it < TSTEPS);
        const bool l1 = (layer == 1) && (it >= 1);
        const bool do_stage = ((it & 7) == 0) && (it + 8 < TSTEPS);

        float4 xs;
        if (do_stage) xs = *(const float4*)(xg + (size_t)(it + 8) * 32);   // in flight over compute

        f32x4 A0 = {b0, b0, b0, b0}, A1 = {b1, b1, b1, b1},
              A2 = {b2, b2, b2, b2}, A3 = {b3, b3, b3, b3};

        if (l0) {
            const short* Xc = &Xb[(it >> 3) & 1][it & 7][0][0];
            const short* Hr = &H0s[(it + 1) & 1][0][0];                    // h0^{it-1}
            const bf16x8 a0 = *(const bf16x8*)(Xc + aoffX);
            const bf16x8 a1 = *(const bf16x8*)(Hr + aoffH);
            const bf16x8 a2 = *(const bf16x8*)(Hr + aoffH + 32);
            A0 = mfma16(a0, B00, A0); A1 = mfma16(a0, B10, A1);
            A2 = mfma16(a0, B20, A2); A3 = mfma16(a0, B30, A3);
            A0 = mfma16(a1, B01, A0); A1 = mfma16(a1, B11, A1);
            A2 = mfma16(a1, B21, A2); A3 = mfma16(a1, B31, A3);
            A0 = mfma16(a2, B02, A0); A1 = mfma16(a2, B12, A1);
            A2 = mfma16(a2, B22, A2); A3 = mfma16(a2, B32, A3);
        } else if (l1) {
            const short* Hr = &H0s[(it + 1) & 1][0][0];                    // h0^{it-1}
            const short* Gr = &H1s[it & 1][0][0];                          // h1^{it-2}
            const bf16x8 a0 = *(const bf16x8*)(Hr + aoffH);
            const bf16x8 a1 = *(const bf16x8*)(Hr + aoffH + 32);
            const bf16x8 a2 = *(const bf16x8*)(Gr + aoffH);
            const bf16x8 a3 = *(const bf16x8*)(Gr + aoffH + 32);
            A0 = mfma16(a0, B00, A0); A1 = mfma16(a0, B10, A1);
            A2 = mfma16(a0, B20, A2); A3 = mfma16(a0, B30, A3);
            A0 = mfma16(a1, B01, A0); A1 = mfma16(a1, B11, A1);
            A2 = mfma16(a1, B21, A2); A3 = mfma16(a1, B31, A3);
            A0 = mfma16(a2, B02, A0); A1 = mfma16(a2, B12, A1);
            A2 = mfma16(a2, B22, A2); A3 = mfma16(a2, B32, A3);
            A0 = mfma16(a3, B03, A0); A1 = mfma16(a3, B13, A1);
            A2 = mfma16(a3, B23, A2); A3 = mfma16(a3, B33, A3);
        }

        if (l0 || l1) {
            // A0=i, A1=f, A2=g(tanh), A3=o; lane value r -> (row q*4+r, cell cidx)
            float h0v, h1v, h2v, h3v;
            {
                const float iv = sigm_p(A0[0]), fv = sigm_p(A1[0]);
                const float gv = tanh_p(A2[0]), ov = sigm_p(A3[0]);
                c0 = fmaf(fv, c0, iv * gv);  h0v = ov * tanh_p(c0 * (2.0f * L2E));
            }
            {
                const float iv = sigm_p(A0[1]), fv = sigm_p(A1[1]);
                const float gv = tanh_p(A2[1]), ov = sigm_p(A3[1]);
                c1 = fmaf(fv, c1, iv * gv);  h1v = ov * tanh_p(c1 * (2.0f * L2E));
            }
            {
                const float iv = sigm_p(A0[2]), fv = sigm_p(A1[2]);
                const float gv = tanh_p(A2[2]), ov = sigm_p(A3[2]);
                c2 = fmaf(fv, c2, iv * gv);  h2v = ov * tanh_p(c2 * (2.0f * L2E));
            }
            {
                const float iv = sigm_p(A0[3]), fv = sigm_p(A1[3]);
                const float gv = tanh_p(A2[3]), ov = sigm_p(A3[3]);
                c3 = fmaf(fv, c3, iv * gv);  h3v = ov * tanh_p(c3 * (2.0f * L2E));
            }
            if (q < 2) {                                   // rows q*4+r in 0..7 valid
                short* hw = l0 ? &H0s[it & 1][0][0] : &H1s[(it + 1) & 1][0][0];
                hw[(q * 4 + 0) * 72 + cidx] = f2bf(h0v);
                hw[(q * 4 + 1) * 72 + cidx] = f2bf(h1v);
                hw[(q * 4 + 2) * 72 + cidx] = f2bf(h2v);
                hw[(q * 4 + 3) * 72 + cidx] = f2bf(h3v);
                if (l1 && it == TSTEPS) {                  // final h1, fp32 for LN
                    HF[q * 4 + 0][cidx] = h0v;
                    HF[q * 4 + 1][cidx] = h1v;
                    HF[q * 4 + 2][cidx] = h2v;
                    HF[q * 4 + 3][cidx] = h3v;
                }
            }
        }

        if (do_stage) {                                    // write next x group (other buffer)
            short4v pk; pk[0] = f2bf(xs.x); pk[1] = f2bf(xs.y);
            pk[2] = f2bf(xs.z); pk[3] = f2bf(xs.w);
            *(short4v*)(&Xb[((it >> 3) + 1) & 1][ss][sm][kq * 4]) = pk;
        }
        __syncthreads();
    }

    // ---- epilogue: LayerNorm + FC, wave per row ----
    {
        const float v = HF[wave][lane];
        float s1 = v, s2 = v * v;
#pragma unroll
        for (int mm = 1; mm < 64; mm <<= 1) {
            s1 += __shfl_xor(s1, mm, 64);
            s2 += __shfl_xor(s2, mm, 64);
        }
        const float mu = s1 * (1.0f / 64.0f);
        float var = s2 * (1.0f / 64.0f) - mu * mu;
        var = fmaxf(var, 0.0f);
        const float rs = rsqrtf(var + 1e-5f);
        float p = ((v - mu) * rs * ln_g[lane] + ln_b[lane]) * fcw[lane];
#pragma unroll
        for (int mm = 1; mm < 64; mm <<= 1) p += __shfl_xor(p, mm, 64);
        if (lane == 0) out[rb + wave] = p + fcb[0];
    }
}

extern "C" void kernel_launch(void* const* d_in, const int* in_sizes, int n_in,
                              void* d_out, int out_size, void* d_ws, size_t ws_size,
                              hipStream_t stream) {
    const float* x    = (const float*)d_in[0];
    const float* Wih0 = (const float*)d_in[1];
    const float* Whh0 = (const float*)d_in[2];
    const float* bih0 = (const float*)d_in[3];
    const float* bhh0 = (const float*)d_in[4];
    const float* Wih1 = (const float*)d_in[5];
    const float* Whh1 = (const float*)d_in[6];
    const float* bih1 = (const float*)d_in[7];
    const float* bhh1 = (const float*)d_in[8];
    const float* ln_g = (const float*)d_in[9];
    const float* ln_b = (const float*)d_in[10];
    const float* fcw  = (const float*)d_in[11];
    const float* fcb  = (const float*)d_in[12];

    dim3 grid(2048 / RPB);    // 256 blocks -> 1 per CU
    dim3 block(512);
    hipLaunchKernelGGL(lstm_mfma_68547678044465, grid, block, 0, stream,
                       x, Wih0, Whh0, bih0, bhh0, Wih1, Whh1, bih1, bhh1,
                       ln_g, ln_b, fcw, fcb, (float*)d_out);
}

// Round 6
// 521.094 us; speedup vs baseline: 213.4484x; 1.2487x over previous
//
#include <hip/hip_runtime.h>
#include <math.h>

#define TSTEPS 512
#define RPB 8
#define L2E  1.4426950408889634f
#define L2E2 2.8853900817779268f   // 2*log2(e)

typedef __attribute__((ext_vector_type(4))) short short4v;
typedef __attribute__((ext_vector_type(8))) short short8;
typedef __attribute__((ext_vector_type(4))) float f32x4;
typedef __bf16 bf16x8 __attribute__((ext_vector_type(8)));

__device__ __forceinline__ short f2bf(float f) {            // RNE float->bf16
    union { float f; unsigned u; } v; v.f = f;
    return (short)((v.u + 0x7FFFu + ((v.u >> 16) & 1u)) >> 16);
}
__device__ __forceinline__ float rcp_f(float x) { return __builtin_amdgcn_rcpf(x); }
__device__ __forceinline__ float ex2(float x)   { return __builtin_amdgcn_exp2f(x); }
__device__ __forceinline__ float sigm_p(float v) { return rcp_f(1.0f + ex2(-v)); }   // v = x*log2e
__device__ __forceinline__ float tanh_p(float v) {                                    // v = x*2log2e
    return fmaf(-2.0f, rcp_f(1.0f + ex2(v)), 1.0f);        // 1 - 2/(1+e^{2x}): no abs/copysign
}
__device__ __forceinline__ f32x4 mfma16(bf16x8 a, bf16x8 b, f32x4 c) {
    return __builtin_amdgcn_mfma_f32_16x16x32_bf16(a, b, c, 0, 0, 0);
}

// 256 blocks x 256 threads (4 waves). Both layers merged into ONE 16x16 MFMA
// tile via block-diagonal K-packing (K=224):
//   A rows 0-7  = [x_t (32) | h0^{t-1} (64) | 0 (128)]        -> L0 step t
//   A rows 8-15 = [0 (96)   | h0^{t-1} (64) | h1^{t-2} (64)]  -> L1 step t-1
//   B rows: 0-31 Wih0, 32-95 Whh0, 96-159 Wih1, 160-223 Whh1 (dense, in regs)
// Zero A-blocks come from reading LDS with +/-8-row offsets into zero-padded
// rows that are never written. All 64 lanes' C values are valid cells ->
// activation (transcendental) work per CU-iter is halved vs the RPB=8 split.
// Wave wl owns gate tiles {64g + 16*wl}: lane has i,f,g,o for the same cell;
// c stays fp32 in registers (per-lane layer chosen by q = lane>>4: q<2 -> L0).
__global__ __launch_bounds__(256)
void lstm_mfma_68547678044465(const float* __restrict__ x,
                              const float* __restrict__ Wih0, const float* __restrict__ Whh0,
                              const float* __restrict__ bih0, const float* __restrict__ bhh0,
                              const float* __restrict__ Wih1, const float* __restrict__ Whh1,
                              const float* __restrict__ bih1, const float* __restrict__ bhh1,
                              const float* __restrict__ ln_g, const float* __restrict__ ln_b,
                              const float* __restrict__ fcw, const float* __restrict__ fcb,
                              float* __restrict__ out)
{
    __shared__ __align__(16) short XB[2][8][16][40];  // x bf16; rows 8-15 always zero
    __shared__ __align__(16) short HA[2][24][72];     // rows 0-7 zero | 8-15 h0 | 16-23 zero
    __shared__ __align__(16) short HC[2][16][72];     // rows 0-7 zero | 8-15 h1
    __shared__ __align__(16) float HF[8][64];         // final h1 fp32 for LN

    const int tid  = threadIdx.x;
    const int wl   = tid >> 6;           // wave 0..3
    const int lane = tid & 63;
    const int n    = lane & 15;          // A row m / C col n
    const int q    = lane >> 4;          // k-quad / C row group
    const int rb   = blockIdx.x * RPB;
    const int cell = wl * 16 + n;        // h-dim cell 0..63

    // ---- B-fragments: 4 gate-tiles x 7 K-chunks, named registers ----
    auto loadB = [&](const float* wrow, float sc) -> bf16x8 {
        const float4 lo = *(const float4*)(wrow);
        const float4 hi = *(const float4*)(wrow + 4);
        short8 r;
        r[0] = f2bf(lo.x * sc); r[1] = f2bf(lo.y * sc);
        r[2] = f2bf(lo.z * sc); r[3] = f2bf(lo.w * sc);
        r[4] = f2bf(hi.x * sc); r[5] = f2bf(hi.y * sc);
        r[6] = f2bf(hi.z * sc); r[7] = f2bf(hi.w * sc);
        return (bf16x8)r;
    };
    const int g0 = cell, g1 = 64 + cell, g2 = 128 + cell, g3 = 192 + cell;
    const int ko = q * 8;
    const bf16x8 B0_0 = loadB(Wih0 + g0 * 32 + ko, L2E);
    const bf16x8 B0_1 = loadB(Whh0 + g0 * 64 + ko, L2E);
    const bf16x8 B0_2 = loadB(Whh0 + g0 * 64 + 32 + ko, L2E);
    const bf16x8 B0_3 = loadB(Wih1 + g0 * 64 + ko, L2E);
    const bf16x8 B0_4 = loadB(Wih1 + g0 * 64 + 32 + ko, L2E);
    const bf16x8 B0_5 = loadB(Whh1 + g0 * 64 + ko, L2E);
    const bf16x8 B0_6 = loadB(Whh1 + g0 * 64 + 32 + ko, L2E);
    const bf16x8 B1_0 = loadB(Wih0 + g1 * 32 + ko, L2E);
    const bf16x8 B1_1 = loadB(Whh0 + g1 * 64 + ko, L2E);
    const bf16x8 B1_2 = loadB(Whh0 + g1 * 64 + 32 + ko, L2E);
    const bf16x8 B1_3 = loadB(Wih1 + g1 * 64 + ko, L2E);
    const bf16x8 B1_4 = loadB(Wih1 + g1 * 64 + 32 + ko, L2E);
    const bf16x8 B1_5 = loadB(Whh1 + g1 * 64 + ko, L2E);
    const bf16x8 B1_6 = loadB(Whh1 + g1 * 64 + 32 + ko, L2E);
    const bf16x8 B2_0 = loadB(Wih0 + g2 * 32 + ko, L2E2);
    const bf16x8 B2_1 = loadB(Whh0 + g2 * 64 + ko, L2E2);
    const bf16x8 B2_2 = loadB(Whh0 + g2 * 64 + 32 + ko, L2E2);
    const bf16x8 B2_3 = loadB(Wih1 + g2 * 64 + ko, L2E2);
    const bf16x8 B2_4 = loadB(Wih1 + g2 * 64 + 32 + ko, L2E2);
    const bf16x8 B2_5 = loadB(Whh1 + g2 * 64 + ko, L2E2);
    const bf16x8 B2_6 = loadB(Whh1 + g2 * 64 + 32 + ko, L2E2);
    const bf16x8 B3_0 = loadB(Wih0 + g3 * 32 + ko, L2E);
    const bf16x8 B3_1 = loadB(Whh0 + g3 * 64 + ko, L2E);
    const bf16x8 B3_2 = loadB(Whh0 + g3 * 64 + 32 + ko, L2E);
    const bf16x8 B3_3 = loadB(Wih1 + g3 * 64 + ko, L2E);
    const bf16x8 B3_4 = loadB(Wih1 + g3 * 64 + 32 + ko, L2E);
    const bf16x8 B3_5 = loadB(Whh1 + g3 * 64 + ko, L2E);
    const bf16x8 B3_6 = loadB(Whh1 + g3 * 64 + 32 + ko, L2E);

    // ---- biases: per-lane layer select (q<2 -> L0 rows, q>=2 -> L1 rows) ----
    float b0, b1, b2, b3;
    if (q < 2) {
        b0 = (bih0[g0] + bhh0[g0]) * L2E;  b1 = (bih0[g1] + bhh0[g1]) * L2E;
        b2 = (bih0[g2] + bhh0[g2]) * L2E2; b3 = (bih0[g3] + bhh0[g3]) * L2E;
    } else {
        b0 = (bih1[g0] + bhh1[g0]) * L2E;  b1 = (bih1[g1] + bhh1[g1]) * L2E;
        b2 = (bih1[g2] + bhh1[g2]) * L2E2; b3 = (bih1[g3] + bhh1[g3]) * L2E;
    }

    // ---- zero all LDS (zero rows must stay zero; parity bufs start 0) ----
    { int* z = (int*)XB; for (int i = tid; i < 5120; i += 256) z[i] = 0; }
    { int* z = (int*)HA; for (int i = tid; i < 1728; i += 256) z[i] = 0; }
    { int* z = (int*)HC; for (int i = tid; i < 1152; i += 256) z[i] = 0; }

    // ---- x staging: lane -> (step ss, row sm, quad kq), 2 float4 per group ----
    const int ss = tid >> 5, sm = (tid >> 2) & 7, kq = tid & 3;
    const float* xrow = x + (size_t)(rb + sm) * (TSTEPS * 32);
    float4 xr0, xr1;
    auto xstore = [&](int buf) {
        short4v pa; pa[0] = f2bf(xr0.x); pa[1] = f2bf(xr0.y);
        pa[2] = f2bf(xr0.z); pa[3] = f2bf(xr0.w);
        *(short4v*)&XB[buf][ss][sm][kq * 4] = pa;
        short4v pb; pb[0] = f2bf(xr1.x); pb[1] = f2bf(xr1.y);
        pb[2] = f2bf(xr1.z); pb[3] = f2bf(xr1.w);
        *(short4v*)&XB[buf][ss][sm][kq * 4 + 16] = pb;
    };
    xr0 = *(const float4*)(xrow + ss * 32 + kq * 4);
    xr1 = *(const float4*)(xrow + ss * 32 + kq * 4 + 16);
    xstore(0);
    __syncthreads();

    float c0 = 0.0f, c1 = 0.0f, c2 = 0.0f, c3 = 0.0f;
    const int aX  = n * 40 + q * 8;                 // XB in-slot offset
    const int aH1 = (8 + n) * 72 + q * 8;           // HA rows 8+m (h0 | Z1)
    const int aH2 = n * 72 + q * 8;                 // HA rows m   (Z0 | h0); same for HC

#pragma unroll 1
    for (int it = 0; it <= TSTEPS; ++it) {
        const int p = it & 1;

        if (((it & 7) == 0) && (it + 8 < TSTEPS)) {            // prefetch next group
            const size_t o = (size_t)(it + 8 + ss) * 32 + kq * 4;
            xr0 = *(const float4*)(xrow + o);
            xr1 = *(const float4*)(xrow + o + 16);
        }

        // ---- A fragments ----
        const short* xb = &XB[(it >> 3) & 1][it & 7][0][0];
        const short* ha = &HA[p][0][0];
        const short* hc = &HC[p][0][0];
        const bf16x8 a0 = *(const bf16x8*)(xb + aX);           // x_t      (rows 8-15: 0)
        const bf16x8 a1 = *(const bf16x8*)(ha + aH1);          // h0 k 0-31  for rows 0-7
        const bf16x8 a2 = *(const bf16x8*)(ha + aH1 + 32);     // h0 k 32-63 for rows 0-7
        const bf16x8 a3 = *(const bf16x8*)(ha + aH2);          // h0 k 0-31  for rows 8-15
        const bf16x8 a4 = *(const bf16x8*)(ha + aH2 + 32);     // h0 k 32-63 for rows 8-15
        const bf16x8 a5 = *(const bf16x8*)(hc + aH2);          // h1 k 0-31  for rows 8-15
        const bf16x8 a6 = *(const bf16x8*)(hc + aH2 + 32);     // h1 k 32-63 for rows 8-15

        f32x4 A0 = {b0, b0, b0, b0}, A1 = {b1, b1, b1, b1},
              A2 = {b2, b2, b2, b2}, A3 = {b3, b3, b3, b3};
        A0 = mfma16(a0, B0_0, A0); A1 = mfma16(a0, B1_0, A1);
        A2 = mfma16(a0, B2_0, A2); A3 = mfma16(a0, B3_0, A3);
        A0 = mfma16(a1, B0_1, A0); A1 = mfma16(a1, B1_1, A1);
        A2 = mfma16(a1, B2_1, A2); A3 = mfma16(a1, B3_1, A3);
        A0 = mfma16(a2, B0_2, A0); A1 = mfma16(a2, B1_2, A1);
        A2 = mfma16(a2, B2_2, A2); A3 = mfma16(a2, B3_2, A3);
        A0 = mfma16(a3, B0_3, A0); A1 = mfma16(a3, B1_3, A1);
        A2 = mfma16(a3, B2_3, A2); A3 = mfma16(a3, B3_3, A3);
        A0 = mfma16(a4, B0_4, A0); A1 = mfma16(a4, B1_4, A1);
        A2 = mfma16(a4, B2_4, A2); A3 = mfma16(a4, B3_4, A3);
        A0 = mfma16(a5, B0_5, A0); A1 = mfma16(a5, B1_5, A1);
        A2 = mfma16(a5, B2_5, A2); A3 = mfma16(a5, B3_5, A3);
        A0 = mfma16(a6, B0_6, A0); A1 = mfma16(a6, B1_6, A1);
        A2 = mfma16(a6, B2_6, A2); A3 = mfma16(a6, B3_6, A3);

        // ---- activations + c update (all lanes valid) ----
        // L1 lanes (q>=2) at it==0 would compute phantom step -1: freeze c, skip store
        const bool freeze = (it == 0) && (q >= 2);
        float hv0, hv1, hv2, hv3;
        {
            const float iv = sigm_p(A0[0]), fv = sigm_p(A1[0]);
            const float gv = tanh_p(A2[0]), ov = sigm_p(A3[0]);
            const float cn = fmaf(fv, c0, iv * gv);
            c0 = freeze ? 0.0f : cn;
            hv0 = ov * tanh_p(c0 * L2E2);
        }
        {
            const float iv = sigm_p(A0[1]), fv = sigm_p(A1[1]);
            const float gv = tanh_p(A2[1]), ov = sigm_p(A3[1]);
            const float cn = fmaf(fv, c1, iv * gv);
            c1 = freeze ? 0.0f : cn;
            hv1 = ov * tanh_p(c1 * L2E2);
        }
        {
            const float iv = sigm_p(A0[2]), fv = sigm_p(A1[2]);
            const float gv = tanh_p(A2[2]), ov = sigm_p(A3[2]);
            const float cn = fmaf(fv, c2, iv * gv);
            c2 = freeze ? 0.0f : cn;
            hv2 = ov * tanh_p(c2 * L2E2);
        }
        {
            const float iv = sigm_p(A0[3]), fv = sigm_p(A1[3]);
            const float gv = tanh_p(A2[3]), ov = sigm_p(A3[3]);
            const float cn = fmaf(fv, c3, iv * gv);
            c3 = freeze ? 0.0f : cn;
            hv3 = ov * tanh_p(c3 * L2E2);
        }

        // ---- h store into parity p^1 (h0 -> HA data rows, h1 -> HC data rows) ----
        {
            short* hd = (q < 2) ? &HA[p ^ 1][8 + (q & 1) * 4][0]
                                : &HC[p ^ 1][8 + (q & 1) * 4][0];
            hd += cell;
            if (!freeze) {
                hd[0]       = f2bf(hv0);
                hd[72]      = f2bf(hv1);
                hd[144]     = f2bf(hv2);
                hd[216]     = f2bf(hv3);
            }
        }
        if ((it == TSTEPS) && (q >= 2)) {               // final h1 (step T-1), fp32
            const int rl = (q & 1) * 4;
            HF[rl + 0][cell] = hv0;
            HF[rl + 1][cell] = hv1;
            HF[rl + 2][cell] = hv2;
            HF[rl + 3][cell] = hv3;
        }

        if (((it & 7) == 6) && (it + 2 < TSTEPS)) xstore(((it >> 3) + 1) & 1);
        __syncthreads();
    }

    // ---- epilogue: LayerNorm + FC; each wave handles 2 rows ----
    const float lg = ln_g[lane], lb = ln_b[lane], fw = fcw[lane], fb = fcb[0];
#pragma unroll
    for (int rr = 0; rr < 2; ++rr) {
        const int row = wl * 2 + rr;
        const float v = HF[row][lane];
        float s1 = v, sq = v * v;
#pragma unroll
        for (int mm = 1; mm < 64; mm <<= 1) {
            s1 += __shfl_xor(s1, mm, 64);
            sq += __shfl_xor(sq, mm, 64);
        }
        const float mu = s1 * (1.0f / 64.0f);
        float var = sq * (1.0f / 64.0f) - mu * mu;
        var = fmaxf(var, 0.0f);
        const float rs = rsqrtf(var + 1e-5f);
        float pv = ((v - mu) * rs * lg + lb) * fw;
#pragma unroll
        for (int mm = 1; mm < 64; mm <<= 1) pv += __shfl_xor(pv, mm, 64);
        if (lane == 0) out[rb + row] = pv + fb;
    }
}

extern "C" void kernel_launch(void* const* d_in, const int* in_sizes, int n_in,
                              void* d_out, int out_size, void* d_ws, size_t ws_size,
                              hipStream_t stream) {
    const float* x    = (const float*)d_in[0];
    const float* Wih0 = (const float*)d_in[1];
    const float* Whh0 = (const float*)d_in[2];
    const float* bih0 = (const float*)d_in[3];
    const float* bhh0 = (const float*)d_in[4];
    const float* Wih1 = (const float*)d_in[5];
    const float* Whh1 = (const float*)d_in[6];
    const float* bih1 = (const float*)d_in[7];
    const float* bhh1 = (const float*)d_in[8];
    const float* ln_g = (const float*)d_in[9];
    const float* ln_b = (const float*)d_in[10];
    const float* fcw  = (const float*)d_in[11];
    const float* fcb  = (const float*)d_in[12];

    dim3 grid(2048 / RPB);    // 256 blocks -> 1 per CU
    dim3 block(256);          // 4 waves: 1 per SIMD
    hipLaunchKernelGGL(lstm_mfma_68547678044465, grid, block, 0, stream,
                       x, Wih0, Whh0, bih0, bhh0, Wih1, Whh1, bih1, bhh1,
                       ln_g, ln_b, fcw, fcb, (float*)d_out);
}